// Round 14
// baseline (187.112 us; speedup 1.0000x reference)
//
#include <hip/hip_runtime.h>

typedef short bf16x8 __attribute__((ext_vector_type(8)));
typedef float f32x4  __attribute__((ext_vector_type(4)));

__device__ __forceinline__ unsigned short f2bf(float f) {
    unsigned int u = __float_as_uint(f);
    u += 0x7FFFu + ((u >> 16) & 1u);
    return (unsigned short)(u >> 16);
}

// tanh-form GELU: x * sigmoid(2*0.79788456*(x + 0.044715 x^3)). |err| <~5e-4 abs.
__device__ __forceinline__ float gelu_f(float x) {
    float x2 = x * x;
    float u = x * (-1.5957691216f - 0.0713548162f * x2);
    float e = __expf(u);
    return x * __builtin_amdgcn_rcpf(1.0f + e);
}

// ---------- fused prep: x cvt + w1 cvt + w2 transpose (one launch) ----------
__global__ void prep_all(const float* __restrict__ x,
                         const float* __restrict__ w1,
                         const float* __restrict__ w2,
                         unsigned short* __restrict__ xb,
                         unsigned short* __restrict__ w1b,
                         unsigned short* __restrict__ w2t) {
    __shared__ float tile[32][33];
    const int b = blockIdx.x, t = threadIdx.x;
    const int tx = t & 31, ty = t >> 5;                   // 32 x 8
    const int o0 = (b % 24) * 32, h0 = (b / 24) * 32;
    #pragma unroll
    for (int r = 0; r < 32; r += 8)
        tile[ty + r][tx] = w2[(size_t)(h0 + ty + r) * 768 + o0 + tx];
    __syncthreads();
    #pragma unroll
    for (int r = 0; r < 32; r += 8) {
        int o = ty + r;
        w2t[(size_t)(o0 + o) * 3072 + h0 + tx] = f2bf(tile[tx][o]);
    }
    constexpr int NX = 16384 * 768 / 4, NW = 3072 * 768 / 4;
    const int stride = gridDim.x * 256;
    for (int i = b * 256 + t; i < NX + NW; i += stride) {
        const float4 v = (i < NX) ? ((const float4*)x)[i] : ((const float4*)w1)[i - NX];
        ushort4 r;
        r.x = f2bf(v.x); r.y = f2bf(v.y); r.z = f2bf(v.z); r.w = f2bf(v.w);
        if (i < NX) ((ushort4*)xb)[i] = r; else ((ushort4*)w1b)[i - NX] = r;
    }
}

// ====== gemm_cs: 256xBN, BK=64, 4-phase, COMPILER-SCHEDULED read->MFMA ======
// R13 delta vs R11/R12 (which serialized {12 ds_reads -> lgkm(0) -> 32 MFMA}
// and plateaued at 37% MfmaUtil across 6 schedule variants):
//  - ds_reads are plain compiler-visible loads; NO asm lgkm before MFMA. The
//    compiler emits partial lgkmcnt(N) waits and interleaves MFMA with the
//    remaining reads (guide §7: its ds_read->MFMA scheduling is near-optimal;
//    my asm lgkmcnt(0)+sched_barrier was defeating it, m141-style).
//  - Phase = {GATE vmcnt(8)+s_barrier; reads(pair P); MFMAs; lgkmcnt(0)
//    [cheap: reads already consumed]; restage P with +2-K-tile data}.
//    WAR: P's reads are lgkm-retired before P is overwritten (in-order DS
//    retirement; even if MFMAs sink, data is already in registers).
//    RAW: P staged end-of-phase X, GATE-certified >=2.5 phases later.
//  - vmcnt ledger (simulated): prologue 16 outstanding; every GATE 12->8;
//    each pair retired >=1 phase before its read; uniform incl. clamped tail.
// Regions (pairs): P1=(A@0,B@32768) buf0-kh0, P2=(A@16384,B@49152) buf0-kh1,
// P3=(A@65536,B@98304) buf1-kh0, P4=(A@81920,B@114688) buf1-kh1. B = A+32768.
// Swizzle (R7-verified, 0 conflicts): 64B rows, phys16Bslot = lg ^ ((row>>1)&3);
// inverse on global source (linear LDS dest), forward on ds_read.
template <int EPI, int K, int N, int BN>
__global__ __launch_bounds__(512, 2) void gemm_cs(
    const unsigned short* __restrict__ A,
    const unsigned short* __restrict__ B,
    const float* __restrict__ bias,
    void* __restrict__ Cp) {
    constexpr int NREP = BN / 64;
    __shared__ __align__(16) char lds[131072];
    const int t = threadIdx.x;
    const int w = t >> 6, l = t & 63;
    constexpr int ntiles = N / BN;

    int bid = blockIdx.x, nwg = gridDim.x;
    int wgid = ((nwg & 7) == 0) ? ((bid & 7) * (nwg >> 3) + (bid >> 3)) : bid;
    const int mt = wgid / ntiles, nt = wgid % ntiles;
    const int m0 = mt << 8, n0 = nt * BN;
    const int wr = w >> 2, wc = w & 3;

    // staging: unit u covers prow=u>>2 (0..255), phys slot u&3; logical slot
    // lg = (u&3) ^ ((prow>>1)&3) = (u&3) ^ ((u>>3)&3); global = prow*K + lg*8.
    const int u1 = t + 512;
    const int gu0 = (t >> 2) * K + (((t & 3) ^ ((t >> 3) & 3)) << 3);
    const int gu1 = (u1 >> 2) * K + (((u1 & 3) ^ ((u1 >> 3) & 3)) << 3);
    const unsigned short* Abase = A + (size_t)m0 * K;
    const unsigned short* Bbase = B + (size_t)n0 * K;

#define STAGE(PTR, KT, KS, REG) { \
    const unsigned short* g_ = (PTR) + (KT) * 64 + (KS) * 32; \
    __builtin_amdgcn_global_load_lds( \
        (const __attribute__((address_space(1))) void*)(g_ + gu0), \
        (__attribute__((address_space(3))) void*)(lds + (REG) + t * 16), 16, 0, 0); \
    __builtin_amdgcn_global_load_lds( \
        (const __attribute__((address_space(1))) void*)(g_ + gu1), \
        (__attribute__((address_space(3))) void*)(lds + (REG) + 8192 + t * 16), 16, 0, 0); }
#define PIN() { asm volatile("" ::: "memory"); }
#define GATE() { asm volatile("s_waitcnt vmcnt(8)\n\ts_barrier" ::: "memory"); }
#define LGKME() { asm volatile("s_waitcnt lgkmcnt(0)" ::: "memory"); }
#define RDB(RG) { const char* p_ = lds + (RG) + boffb; \
    _Pragma("unroll") \
    for (int ni_ = 0; ni_ < NREP; ++ni_) bv[ni_] = *(const bf16x8*)(p_ + ni_ * 1024); }
#define RDA(RG, MH, DST) { const char* p_ = lds + (RG) + aoffb + (MH) * 4096; \
    DST[0] = *(const bf16x8*)(p_);        DST[1] = *(const bf16x8*)(p_ + 1024); \
    DST[2] = *(const bf16x8*)(p_ + 2048); DST[3] = *(const bf16x8*)(p_ + 3072); }
#define MFMAQ(MB, AV) \
    __builtin_amdgcn_s_setprio(1); \
    _Pragma("unroll") \
    for (int mi = 0; mi < 4; ++mi) { \
        _Pragma("unroll") \
        for (int ni = 0; ni < NREP; ++ni) \
            acc[MB * 4 + mi][ni] = __builtin_amdgcn_mfma_f32_16x16x32_bf16( \
                AV[mi], bv[ni], acc[MB * 4 + mi][ni], 0, 0, 0); \
    } \
    __builtin_amdgcn_s_setprio(0);
// Phase: read pair P (region RG for A, RG+32768 for B), MFMA (compiler
// schedules the waits), lgkm-drain, restage P with K-tile SK / k-half SS.
#define PHASE(RG, SK, SS) { \
    GATE(); \
    RDB(RG); RDA(RG, 0, av); RDA(RG, 1, avh); \
    MFMAQ(0, av); MFMAQ(1, avh); \
    LGKME(); \
    STAGE(Abase, SK, SS, RG); PIN(); \
    STAGE(Bbase, SK, SS, (RG) + 32768); PIN(); }

    // ds_read: A frag row = wr*128 + mh*64 + mi*16 + lr, slot cR = l>>4,
    // phys = cR ^ ((row>>1)&3) = cR ^ ((lr>>1)&3). B frag row = wc*(BN/4)+ni*16+lr.
    const int cR = l >> 4, lr = l & 15;
    const int swz = (cR ^ ((lr >> 1) & 3)) << 4;
    const int aoffb = (wr * 128 + lr) * 64 + swz;              // + mh*4096 + mi*1024
    const int boffb = 32768 + (wc * (BN / 4) + lr) * 64 + swz; // + ni*1024

    f32x4 acc[8][NREP];
    {
        f32x4 z = {0.f, 0.f, 0.f, 0.f};
        #pragma unroll
        for (int i = 0; i < 8; ++i)
            #pragma unroll
            for (int j = 0; j < NREP; ++j) acc[i][j] = z;
    }
    bf16x8 av[4], avh[4], bv[NREP];

    constexpr int NTK = K >> 6;        // K-tiles of 64
    constexpr int NT2 = K >> 7;        // main iterations (2 K-tiles each)

    // Prologue: P1<-(t0,kh0), P2<-(t0,kh1), P3<-(t1,kh0), P4<-(t1,kh1);
    // issue order = retirement order expected by the GATE ledger.
    STAGE(Abase, 0, 0, 0);      STAGE(Bbase, 0, 0, 32768);   PIN();
    STAGE(Abase, 0, 1, 16384);  STAGE(Bbase, 0, 1, 49152);   PIN();
    STAGE(Abase, 1, 0, 65536);  STAGE(Bbase, 1, 0, 98304);   PIN();
    STAGE(Abase, 1, 1, 81920);  STAGE(Bbase, 1, 1, 114688);  PIN();

    for (int tt = 0; tt < NT2; ++tt) {
        const int k2 = (2 * tt + 2 < NTK) ? 2 * tt + 2 : NTK - 1;
        const int k3 = (2 * tt + 3 < NTK) ? 2 * tt + 3 : NTK - 1;
        PHASE(0,     k2, 0);   // X1: tile 2t   kh0; restage P1 <- (k2, kh0)
        PHASE(16384, k2, 1);   // X2: tile 2t   kh1; restage P2 <- (k2, kh1)
        PHASE(65536, k3, 0);   // X3: tile 2t+1 kh0; restage P3 <- (k3, kh0)
        PHASE(81920, k3, 1);   // X4: tile 2t+1 kh1; restage P4 <- (k3, kh1)
    }
    asm volatile("s_waitcnt vmcnt(0)" ::: "memory");
#undef STAGE
#undef PIN
#undef GATE
#undef LGKME
#undef RDB
#undef RDA
#undef MFMAQ
#undef PHASE

    // Epilogue. C/D frag: col = lane&15, row = (lane>>4)*4 + j  (m89-verified)
    const int colb = n0 + wc * (BN / 4) + lr;
    if constexpr (EPI == 0) {
        unsigned short* Cb = (unsigned short*)Cp;
        float bvs[NREP];
        #pragma unroll
        for (int ni = 0; ni < NREP; ++ni) bvs[ni] = bias[colb + ni * 16];
        #pragma unroll
        for (int mi = 0; mi < 8; ++mi)
            #pragma unroll
            for (int j = 0; j < 4; ++j) {
                size_t row = m0 + wr * 128 + mi * 16 + cR * 4 + j;
                #pragma unroll
                for (int ni = 0; ni < NREP; ++ni) {
                    float v = acc[mi][ni][j] + bvs[ni];
                    Cb[row * N + colb + ni * 16] = f2bf(gelu_f(v));
                }
            }
    } else {
        float* Cf = (float*)Cp;
        #pragma unroll
        for (int mi = 0; mi < 8; ++mi)
            #pragma unroll
            for (int j = 0; j < 4; ++j) {
                size_t row = m0 + wr * 128 + mi * 16 + cR * 4 + j;
                #pragma unroll
                for (int ni = 0; ni < NREP; ++ni)
                    Cf[row * N + colb + ni * 16] = acc[mi][ni][j];
            }
    }
}

extern "C" void kernel_launch(void* const* d_in, const int* in_sizes, int n_in,
                              void* d_out, int out_size, void* d_ws, size_t ws_size,
                              hipStream_t stream) {
    const float* x  = (const float*)d_in[0];   // [T, 768]
    const float* w1 = (const float*)d_in[1];   // [3072, 768]
    const float* b1 = (const float*)d_in[2];   // [3072]
    const float* w2 = (const float*)d_in[3];   // [3072, 768]
    float* out = (float*)d_out;                // [T, 768] fp32

    const int T = 16384, DIN = 768, DH = 3072, DOUT = 768;

    unsigned short* xb  = (unsigned short*)d_ws;            // T*DIN bf16
    unsigned short* w1b = xb  + (size_t)T * DIN;            // DH*DIN bf16 ([N][K])
    unsigned short* w2t = w1b + (size_t)DH * DIN;           // DOUT*DH bf16 ([N][K])
    unsigned short* h   = w2t + (size_t)DOUT * DH;          // CH*DH bf16
    // NOTE: gemm_cs<...,192> stages 256 B-rows; last n-tile reads 64 rows
    // past w2t into h — allocated, never consumed.

    size_t fixed = ((size_t)T * DIN + (size_t)DH * DIN + (size_t)DOUT * DH) * 2;
    int CH = T;
    while (CH > 256 && fixed + (size_t)CH * DH * 2 > ws_size) CH >>= 1;

    prep_all<<<2304, 256, 0, stream>>>(x, w1, w2, xb, w1b, w2t);

    for (int c0 = 0; c0 < T; c0 += CH) {
        // h = GELU(x_chunk * W1^T + b)      M=CH, N=DH=3072, K=DIN=768, BN=256
        gemm_cs<0, 768, 3072, 256><<<(CH / 256) * (DH / 256), 512, 0, stream>>>(
            xb + (size_t)c0 * DIN, w1b, b1, h);
        // out_chunk = h * W2T^T             M=CH, N=DOUT=768, K=DH=3072, BN=192
        gemm_cs<1, 3072, 768, 192><<<(CH / 256) * (DOUT / 192), 512, 0, stream>>>(
            h, w2t, b1, out + (size_t)c0 * DOUT);
    }
}